// Round 8
// baseline (282.068 us; speedup 1.0000x reference)
//
#include <hip/hip_runtime.h>

typedef unsigned short u16;
typedef __attribute__((ext_vector_type(8))) short bf16x8;   // 8 bf16 (4 VGPRs)
typedef __attribute__((ext_vector_type(4))) float f32x4;    // 16x16 MFMA C/D frag
typedef __attribute__((ext_vector_type(16))) float f32x16;  // 32x32 MFMA C/D frag

__device__ __forceinline__ float bf2f(u16 x) {
  union { unsigned u; float f; } v; v.u = ((unsigned)x) << 16; return v.f;
}
__device__ __forceinline__ u16 f2bf(float f) {
  union { float f; unsigned u; } v; v.f = f;
  unsigned r = v.u + 0x7FFFu + ((v.u >> 16) & 1u);  // RNE
  return (u16)(r >> 16);
}
__device__ __forceinline__ float clampf(float v) {
  return fmaxf(fminf(v, 1.0e4f), -1.0e4f);
}
// async global->LDS, 16B per lane; LDS dest = wave-uniform base + lane*16
__device__ __forceinline__ void gll16(const u16* g, u16* l) {
  __builtin_amdgcn_global_load_lds(
      (const __attribute__((address_space(1))) void*)g,
      (__attribute__((address_space(3))) void*)l, 16, 0, 0);
}
// pack two f32 -> one u32 of 2 bf16 (RNE), lo = first arg
__device__ __forceinline__ unsigned cvtpk(float lo, float hi) {
  unsigned r;
  asm("v_cvt_pk_bf16_f32 %0, %1, %2" : "=v"(r) : "v"(lo), "v"(hi));
  return r;
}

// ---------- convert x (f32) -> bf16 ----------
__global__ __launch_bounds__(256) void convert_x(
    const float* __restrict__ x, u16* __restrict__ xbf) {
  const int i0 = (blockIdx.x * 256 + threadIdx.x) * 4;
  const float4 v = *(const float4*)(x + i0);
  xbf[i0 + 0] = f2bf(v.x); xbf[i0 + 1] = f2bf(v.y);
  xbf[i0 + 2] = f2bf(v.z); xbf[i0 + 3] = f2bf(v.w);
}

// ---------- transpose f32 in[R][C] -> bf16 out[C][R] ----------
__global__ __launch_bounds__(256) void transpose_f32_bf16(
    const float* __restrict__ in, u16* __restrict__ out, int R, int C) {
  __shared__ u16 tile[32][33];
  const int bc = blockIdx.x * 32, br = blockIdx.y * 32;
  const int tx = threadIdx.x & 31, ty = threadIdx.x >> 5;
  #pragma unroll
  for (int i = ty; i < 32; i += 8)
    tile[i][tx] = f2bf(in[(size_t)(br + i) * C + bc + tx]);
  __syncthreads();
  #pragma unroll
  for (int i = ty; i < 32; i += 8)
    out[(size_t)(bc + i) * R + br + tx] = tile[tx][i];
}

// ---------- GEMM1: QKV projection, BK=64 dual 32-col LDS (FROZEN R14) ----------
__global__ __launch_bounds__(256) void gemm1_qkv(
    const u16* __restrict__ A, const u16* __restrict__ Bt,
    const float* __restrict__ bias, u16* __restrict__ qk,
    u16* __restrict__ vt, int K) {
  __shared__ u16 As0[128 * 32], As1[128 * 32];
  __shared__ u16 Bs0[128 * 32], Bs1[128 * 32];
  const int tid = threadIdx.x;
  const int m0 = blockIdx.x * 128, n0 = blockIdx.y * 128;
  const int wave = tid >> 6, lane = tid & 63;
  const int quad = lane >> 4, l16 = lane & 15;
  const int wm = (wave >> 1) * 64, wn = (wave & 1) * 64;
  const int sr = (lane >> 2), sp = lane & 3;

  f32x4 acc[4][4] = {};
  const u16* gA = A + (size_t)(m0 + wave * 32 + sr) * K + sp * 8;
  const u16* gB = Bt + (size_t)(n0 + wave * 32 + sr) * K + sp * 8;

  for (int k0 = 0; k0 < K; k0 += 64) {
    #pragma unroll
    for (int t = 0; t < 2; ++t) {
      gll16(gA + (size_t)(t * 16) * K + k0,      &As0[(wave * 32 + t * 16) * 32]);
      gll16(gA + (size_t)(t * 16) * K + k0 + 32, &As1[(wave * 32 + t * 16) * 32]);
      gll16(gB + (size_t)(t * 16) * K + k0,      &Bs0[(wave * 32 + t * 16) * 32]);
      gll16(gB + (size_t)(t * 16) * K + k0 + 32, &Bs1[(wave * 32 + t * 16) * 32]);
    }
    __syncthreads();
    #pragma unroll
    for (int ks = 0; ks < 2; ++ks) {
      const u16* Ah = ks ? As1 : As0;
      const u16* Bh = ks ? Bs1 : Bs0;
      bf16x8 af[4], bfr[4];
      #pragma unroll
      for (int i = 0; i < 4; ++i)
        af[i] = *(const bf16x8*)&Ah[(wm + i * 16 + l16) * 32 + quad * 8];
      #pragma unroll
      for (int j = 0; j < 4; ++j)
        bfr[j] = *(const bf16x8*)&Bh[(wn + j * 16 + l16) * 32 + quad * 8];
      #pragma unroll
      for (int i = 0; i < 4; ++i)
        #pragma unroll
        for (int j = 0; j < 4; ++j)
          acc[i][j] = __builtin_amdgcn_mfma_f32_16x16x32_bf16(af[i], bfr[j], acc[i][j], 0, 0, 0);
    }
    __syncthreads();
  }

  #pragma unroll
  for (int i = 0; i < 4; ++i) {
    const int row = m0 + wm + i * 16 + quad * 4;
    #pragma unroll
    for (int j = 0; j < 4; ++j) {
      const int col = n0 + wn + j * 16 + l16;
      const float bv = bias[col];
      if (col < 2048) {
        #pragma unroll
        for (int r = 0; r < 4; ++r)
          qk[(size_t)(row + r) * 2048 + col] = f2bf(clampf(acc[i][j][r] + bv));
      } else {
        const int d = col & 63;
        const int hh = (col - 2048) >> 6;
        #pragma unroll
        for (int r = 0; r < 4; ++r) {
          const int rr = row + r;
          const int bb = rr >> 11, ss = rr & 2047;
          vt[(size_t)(bb * 16 + hh) * 131072 + d * 2048 + ss] =
              f2bf(clampf(acc[i][j][r] + bv));
        }
      }
    }
  }
}

// ---------- GEMM2: out(f32) = ctx * w_proj^T + bias (FROZEN R14) ----------
__global__ __launch_bounds__(256) void gemm2_proj(
    const u16* __restrict__ A, const u16* __restrict__ Bt,
    const float* __restrict__ bias, float* __restrict__ out, int K) {
  __shared__ u16 As0[128 * 32], As1[128 * 32];
  __shared__ u16 Bs0[128 * 32], Bs1[128 * 32];
  const int tid = threadIdx.x;
  const int m0 = blockIdx.x * 128, n0 = blockIdx.y * 128;
  const int wave = tid >> 6, lane = tid & 63;
  const int quad = lane >> 4, l16 = lane & 15;
  const int wm = (wave >> 1) * 64, wn = (wave & 1) * 64;
  const int sr = (lane >> 2), sp = lane & 3;

  f32x4 acc[4][4] = {};
  const u16* gA = A + (size_t)(m0 + wave * 32 + sr) * K + sp * 8;
  const u16* gB = Bt + (size_t)(n0 + wave * 32 + sr) * K + sp * 8;

  for (int k0 = 0; k0 < K; k0 += 64) {
    #pragma unroll
    for (int t = 0; t < 2; ++t) {
      gll16(gA + (size_t)(t * 16) * K + k0,      &As0[(wave * 32 + t * 16) * 32]);
      gll16(gA + (size_t)(t * 16) * K + k0 + 32, &As1[(wave * 32 + t * 16) * 32]);
      gll16(gB + (size_t)(t * 16) * K + k0,      &Bs0[(wave * 32 + t * 16) * 32]);
      gll16(gB + (size_t)(t * 16) * K + k0 + 32, &Bs1[(wave * 32 + t * 16) * 32]);
    }
    __syncthreads();
    #pragma unroll
    for (int ks = 0; ks < 2; ++ks) {
      const u16* Ah = ks ? As1 : As0;
      const u16* Bh = ks ? Bs1 : Bs0;
      bf16x8 af[4], bfr[4];
      #pragma unroll
      for (int i = 0; i < 4; ++i)
        af[i] = *(const bf16x8*)&Ah[(wm + i * 16 + l16) * 32 + quad * 8];
      #pragma unroll
      for (int j = 0; j < 4; ++j)
        bfr[j] = *(const bf16x8*)&Bh[(wn + j * 16 + l16) * 32 + quad * 8];
      #pragma unroll
      for (int i = 0; i < 4; ++i)
        #pragma unroll
        for (int j = 0; j < 4; ++j)
          acc[i][j] = __builtin_amdgcn_mfma_f32_16x16x32_bf16(af[i], bfr[j], acc[i][j], 0, 0, 0);
    }
    __syncthreads();
  }

  #pragma unroll
  for (int i = 0; i < 4; ++i) {
    const int row = m0 + wm + i * 16 + quad * 4;
    #pragma unroll
    for (int j = 0; j < 4; ++j) {
      const int col = n0 + wn + j * 16 + l16;
      const float bv = bias[col];
      #pragma unroll
      for (int r = 0; r < 4; ++r)
        out[(size_t)(row + r) * 1024 + col] = clampf(acc[i][j][r] + bv);
    }
  }
}

// ---------- fused flash attention, v14 (resubmit after infra failure) ------
// R7 bench: "MI355X container failed twice" = broker infrastructure error,
// no kernel verdict. Resubmitting v14 unchanged; theory from R6:
//  1. permlane32_swap repack: cA=pk(s0,s1),cB=pk(s2,s3),cC=pk(s4,s5),
//     cD=pk(s6,s7); swap(cA,cC) -> cA=w0,cC=w2; swap(cB,cD) -> cB=w1,cD=w3
//     (swap semantics: vdst.hi <-> vsrc.lo). Exact pf for BOTH lane halves,
//     no selects, no divergence. Replaces 16 ds_bpermute + 16 cndmask/tile
//     with 8 permlane ops (T12 primitive, 1.20x vs bpermute [m255]).
//  2. denominator via ones-MFMA: lsum = mfma(pf, ones, lsum) per 16-k step
//     (+4 MFMA/tile on the 30%-idle matrix pipe) deletes the 30-add scalar
//     tree + epilogue bpermute/LDS broadcast. lsum reg r has the SAME
//     q0(r) mapping as o -> inv = 1/lsum[r] directly. Numerics = v7's
//     proven ones-MFMA denominator (bf16 P in num and denom).
//  3. s_setprio(1) around MFMA clusters (T5: +4-7% attn, m191).
// Geometry/sync FROZEN: grid (64,16), 2 barriers, prefetch-1, LDS exactly
// 36864B -> 4 blocks/CU.
__device__ __forceinline__ int swz(int row, int col) {
  const int key = (row ^ (row >> 2)) & 7;
  return row * 64 + (((col >> 3) ^ key) << 3) + (col & 7);
}

__global__ __launch_bounds__(256, 4) void attn_fused(
    const u16* __restrict__ qk, const u16* __restrict__ vt,
    u16* __restrict__ ctx) {
  __shared__ u16 Ks[64 * 64];
  __shared__ u16 VsT[64 * 64];
  __shared__ u16 big[10240];  // pad to 36864B total (pins 4 blocks/CU)
  const int bh = blockIdx.x, qt = blockIdx.y;
  const int b = bh >> 4, h = bh & 15;
  const int tid = threadIdx.x;
  const int w = tid >> 6, lane = tid & 63;
  const int l31 = lane & 31, hl = lane >> 5;
  const int qbase = qt * 128 + w * 32;

  // Q fragments (B-operand): lane l31 = q-col, elems d = ds*16 + hl*8 + e
  const u16* qptr = qk + (size_t)(b * 2048) * 2048 + h * 64;
  bf16x8 qf[4];
  #pragma unroll
  for (int ds = 0; ds < 4; ++ds)
    qf[ds] = *(const bf16x8*)(qptr + (size_t)(qbase + l31) * 2048 + ds * 16 + hl * 8);

  const u16* kptr = qk + (size_t)(b * 2048) * 2048 + 1024 + h * 64;
  const u16* vptr = vt + (size_t)bh * 131072;

  const int srow = tid >> 3, scol = (tid & 7) * 8;

  // loop-invariant LDS offsets
  const int st0 = swz(srow, scol);
  const int st1 = swz(srow + 32, scol);
  int off[2][4];
  #pragma unroll
  for (int a = 0; a < 2; ++a)
    #pragma unroll
    for (int d = 0; d < 4; ++d)
      off[a][d] = swz(a * 32 + l31, d * 16 + hl * 8);

  // loop-invariant global bases
  const u16* kB0 = kptr + (size_t)srow * 2048 + scol;
  const u16* kB1 = kptr + (size_t)(srow + 32) * 2048 + scol;
  const u16* vB0 = vptr + (size_t)srow * 2048 + scol;
  const u16* vB1 = vptr + (size_t)(srow + 32) * 2048 + scol;

  f32x16 o[2] = {};
  f32x16 lsum = {};
  const short one = (short)0x3F80;  // bf16 1.0
  const bf16x8 ones = {one, one, one, one, one, one, one, one};
  const float c2 = 0.125f * 1.44269504088896340736f;

  bf16x8 k0 = *(const bf16x8*)kB0;
  bf16x8 k1 = *(const bf16x8*)kB1;
  bf16x8 v0 = *(const bf16x8*)vB0;
  bf16x8 v1 = *(const bf16x8*)vB1;

  for (int kv0 = 0; kv0 < 2048; kv0 += 64) {
    __syncthreads();
    *(bf16x8*)&Ks[st0]  = k0;
    *(bf16x8*)&Ks[st1]  = k1;
    *(bf16x8*)&VsT[st0] = v0;
    *(bf16x8*)&VsT[st1] = v1;
    __syncthreads();
    const int kvn = (kv0 + 64) & 2047;
    k0 = *(const bf16x8*)(kB0 + (size_t)kvn * 2048);
    k1 = *(const bf16x8*)(kB1 + (size_t)kvn * 2048);
    v0 = *(const bf16x8*)(vB0 + kvn);
    v1 = *(const bf16x8*)(vB1 + kvn);

    #pragma unroll
    for (int kb = 0; kb < 2; ++kb) {
      // QK^T swapped: s^T[k][q], lane col = q, regs = k rows
      f32x16 s = {};
      __builtin_amdgcn_s_setprio(1);
      #pragma unroll
      for (int ds = 0; ds < 4; ++ds) {
        bf16x8 kf = *(const bf16x8*)&Ks[off[kb][ds]];
        s = __builtin_amdgcn_mfma_f32_32x32x16_bf16(kf, qf[ds], s, 0, 0, 0);
      }
      __builtin_amdgcn_s_setprio(0);
      // exp2 in place
      #pragma unroll
      for (int r = 0; r < 16; ++r)
        s[r] = __builtin_amdgcn_exp2f(s[r] * c2);
      // PV: A-frag via cvt_pk + permlane32_swap (no bpermute, no selects)
      #pragma unroll
      for (int ksl = 0; ksl < 2; ++ksl) {
        const int r0 = ksl * 8;
        unsigned cA = cvtpk(s[r0 + 0], s[r0 + 1]);
        unsigned cB = cvtpk(s[r0 + 2], s[r0 + 3]);
        unsigned cC = cvtpk(s[r0 + 4], s[r0 + 5]);
        unsigned cD = cvtpk(s[r0 + 6], s[r0 + 7]);
        // swap vdst.hi <-> vsrc.lo: cA becomes w0, cC becomes w2 (both halves)
        asm volatile("v_permlane32_swap_b32 %0, %1" : "+v"(cA), "+v"(cC));
        asm volatile("v_permlane32_swap_b32 %0, %1" : "+v"(cB), "+v"(cD));
        union { unsigned u[4]; bf16x8 v; } pf;
        pf.u[0] = cA;  // e=0,1
        pf.u[1] = cB;  // e=2,3
        pf.u[2] = cC;  // e=4,5
        pf.u[3] = cD;  // e=6,7
        const int kg = kb * 2 + ksl;
        __builtin_amdgcn_s_setprio(1);
        lsum = __builtin_amdgcn_mfma_f32_32x32x16_bf16(pf.v, ones, lsum, 0, 0, 0);
        #pragma unroll
        for (int db = 0; db < 2; ++db) {
          bf16x8 vf = *(const bf16x8*)&VsT[off[db][kg]];
          o[db] = __builtin_amdgcn_mfma_f32_32x32x16_bf16(pf.v, vf, o[db], 0, 0, 0);
        }
        __builtin_amdgcn_s_setprio(0);
      }
    }
  }

  // vestigial store keeps `big` referenced (pins LDS_Block_Size = 36864)
  if (lane < 32) ((float*)big)[w * 32 + lane] = lsum[0];

  u16* cbase = ctx + (size_t)(b * 2048) * 1024 + h * 64;
  #pragma unroll
  for (int r = 0; r < 16; ++r) {
    const int q0 = (r & 3) + 8 * (r >> 2) + 4 * hl;
    const float inv = 1.0f / lsum[r];
    const size_t qrow = (size_t)(qbase + q0);
    cbase[qrow * 1024 + l31]      = f2bf(o[0][r] * inv);
    cbase[qrow * 1024 + 32 + l31] = f2bf(o[1][r] * inv);
  }
}

extern "C" void kernel_launch(void* const* d_in, const int* in_sizes, int n_in,
                              void* d_out, int out_size, void* d_ws, size_t ws_size,
                              hipStream_t stream) {
  (void)out_size;
  const float *x = nullptr, *wq = nullptr, *bq = nullptr, *wp = nullptr, *bp = nullptr;
  for (int i = 0; i < n_in; ++i) {
    switch (in_sizes[i]) {
      case 8388608: x  = (const float*)d_in[i]; break;
      case 3145728: wq = (const float*)d_in[i]; break;
      case 3072:    bq = (const float*)d_in[i]; break;
      case 1048576: wp = (const float*)d_in[i]; break;
      case 1024:    bp = (const float*)d_in[i]; break;
      default: break;
    }
  }
  if (!x || !wq || !bq || !wp || !bp) {
    x  = (const float*)d_in[0]; wq = (const float*)d_in[1];
    bq = (const float*)d_in[2]; wp = (const float*)d_in[3];
    bp = (const float*)d_in[4];
  }
  float* out = (float*)d_out;

  const size_t NEED = 75497472;
  if (ws_size < NEED) return;

  char* ws = (char*)d_ws;
  u16* qkb = (u16*)(ws);              // [8192][2048] Q,K
  u16* vt  = (u16*)(ws + 33554432);   // [64][64][2048] V^T
  u16* xbf = (u16*)(ws + 50331648);   // x_bf, then ctx
  u16* wT1 = (u16*)(ws + 67108864);
  u16* wT2 = (u16*)(ws + 73400320);

  convert_x<<<8192, 256, 0, stream>>>(x, xbf);
  transpose_f32_bf16<<<dim3(96, 32), 256, 0, stream>>>(wq, wT1, 1024, 3072);
  transpose_f32_bf16<<<dim3(32, 32), 256, 0, stream>>>(wp, wT2, 1024, 1024);
  gemm1_qkv<<<dim3(64, 24), 256, 0, stream>>>(xbf, wT1, bq, qkb, vt, 1024);
  attn_fused<<<dim3(64, 16), 256, 0, stream>>>(qkb, vt, xbf /*ctx*/);
  gemm2_proj<<<dim3(64, 8), 256, 0, stream>>>(xbf /*ctx*/, wT2, bp, out, 1024);
}

// Round 9
// 279.866 us; speedup vs baseline: 1.0079x; 1.0079x over previous
//
#include <hip/hip_runtime.h>

typedef unsigned short u16;
typedef __attribute__((ext_vector_type(8))) short bf16x8;   // 8 bf16 (4 VGPRs)
typedef __attribute__((ext_vector_type(4))) float f32x4;    // 16x16 MFMA C/D frag
typedef __attribute__((ext_vector_type(16))) float f32x16;  // 32x32 MFMA C/D frag

__device__ __forceinline__ float bf2f(u16 x) {
  union { unsigned u; float f; } v; v.u = ((unsigned)x) << 16; return v.f;
}
__device__ __forceinline__ u16 f2bf(float f) {
  union { float f; unsigned u; } v; v.f = f;
  unsigned r = v.u + 0x7FFFu + ((v.u >> 16) & 1u);  // RNE
  return (u16)(r >> 16);
}
__device__ __forceinline__ float clampf(float v) {
  return fmaxf(fminf(v, 1.0e4f), -1.0e4f);
}
// async global->LDS, 16B per lane; LDS dest = wave-uniform base + lane*16
__device__ __forceinline__ void gll16(const u16* g, u16* l) {
  __builtin_amdgcn_global_load_lds(
      (const __attribute__((address_space(1))) void*)g,
      (__attribute__((address_space(3))) void*)l, 16, 0, 0);
}
// pack two f32 -> one u32 of 2 bf16 (RNE), lo = first arg
__device__ __forceinline__ unsigned cvtpk(float lo, float hi) {
  unsigned r;
  asm("v_cvt_pk_bf16_f32 %0, %1, %2" : "=v"(r) : "v"(lo), "v"(hi));
  return r;
}

// ---------- convert x (f32) -> bf16 ----------
__global__ __launch_bounds__(256) void convert_x(
    const float* __restrict__ x, u16* __restrict__ xbf) {
  const int i0 = (blockIdx.x * 256 + threadIdx.x) * 4;
  const float4 v = *(const float4*)(x + i0);
  xbf[i0 + 0] = f2bf(v.x); xbf[i0 + 1] = f2bf(v.y);
  xbf[i0 + 2] = f2bf(v.z); xbf[i0 + 3] = f2bf(v.w);
}

// ---------- transpose f32 in[R][C] -> bf16 out[C][R] ----------
__global__ __launch_bounds__(256) void transpose_f32_bf16(
    const float* __restrict__ in, u16* __restrict__ out, int R, int C) {
  __shared__ u16 tile[32][33];
  const int bc = blockIdx.x * 32, br = blockIdx.y * 32;
  const int tx = threadIdx.x & 31, ty = threadIdx.x >> 5;
  #pragma unroll
  for (int i = ty; i < 32; i += 8)
    tile[i][tx] = f2bf(in[(size_t)(br + i) * C + bc + tx]);
  __syncthreads();
  #pragma unroll
  for (int i = ty; i < 32; i += 8)
    out[(size_t)(bc + i) * R + br + tx] = tile[tx][i];
}

// ---------- GEMM1: QKV projection (R15: Q output pre-scaled by c2) ----------
// c2 = 0.125 * log2(e) folded into Q at write time: Q' = clampf(q) * c2.
// One bf16 rounding either way (was rnd(q)*c2 in f32 at attn; now rnd(q*c2)),
// so error budget unchanged. attn computes exp2(s) with NO per-score mul.
__global__ __launch_bounds__(256) void gemm1_qkv(
    const u16* __restrict__ A, const u16* __restrict__ Bt,
    const float* __restrict__ bias, u16* __restrict__ qk,
    u16* __restrict__ vt, int K) {
  __shared__ u16 As0[128 * 32], As1[128 * 32];
  __shared__ u16 Bs0[128 * 32], Bs1[128 * 32];
  const int tid = threadIdx.x;
  const int m0 = blockIdx.x * 128, n0 = blockIdx.y * 128;
  const int wave = tid >> 6, lane = tid & 63;
  const int quad = lane >> 4, l16 = lane & 15;
  const int wm = (wave >> 1) * 64, wn = (wave & 1) * 64;
  const int sr = (lane >> 2), sp = lane & 3;

  f32x4 acc[4][4] = {};
  const u16* gA = A + (size_t)(m0 + wave * 32 + sr) * K + sp * 8;
  const u16* gB = Bt + (size_t)(n0 + wave * 32 + sr) * K + sp * 8;

  for (int k0 = 0; k0 < K; k0 += 64) {
    #pragma unroll
    for (int t = 0; t < 2; ++t) {
      gll16(gA + (size_t)(t * 16) * K + k0,      &As0[(wave * 32 + t * 16) * 32]);
      gll16(gA + (size_t)(t * 16) * K + k0 + 32, &As1[(wave * 32 + t * 16) * 32]);
      gll16(gB + (size_t)(t * 16) * K + k0,      &Bs0[(wave * 32 + t * 16) * 32]);
      gll16(gB + (size_t)(t * 16) * K + k0 + 32, &Bs1[(wave * 32 + t * 16) * 32]);
    }
    __syncthreads();
    #pragma unroll
    for (int ks = 0; ks < 2; ++ks) {
      const u16* Ah = ks ? As1 : As0;
      const u16* Bh = ks ? Bs1 : Bs0;
      bf16x8 af[4], bfr[4];
      #pragma unroll
      for (int i = 0; i < 4; ++i)
        af[i] = *(const bf16x8*)&Ah[(wm + i * 16 + l16) * 32 + quad * 8];
      #pragma unroll
      for (int j = 0; j < 4; ++j)
        bfr[j] = *(const bf16x8*)&Bh[(wn + j * 16 + l16) * 32 + quad * 8];
      #pragma unroll
      for (int i = 0; i < 4; ++i)
        #pragma unroll
        for (int j = 0; j < 4; ++j)
          acc[i][j] = __builtin_amdgcn_mfma_f32_16x16x32_bf16(af[i], bfr[j], acc[i][j], 0, 0, 0);
    }
    __syncthreads();
  }

  const float c2q = 0.125f * 1.44269504088896340736f;
  #pragma unroll
  for (int i = 0; i < 4; ++i) {
    const int row = m0 + wm + i * 16 + quad * 4;
    #pragma unroll
    for (int j = 0; j < 4; ++j) {
      const int col = n0 + wn + j * 16 + l16;
      const float bv = bias[col];
      if (col < 1024) {  // Q: pre-scale by c2
        #pragma unroll
        for (int r = 0; r < 4; ++r)
          qk[(size_t)(row + r) * 2048 + col] = f2bf(clampf(acc[i][j][r] + bv) * c2q);
      } else if (col < 2048) {  // K: unscaled
        #pragma unroll
        for (int r = 0; r < 4; ++r)
          qk[(size_t)(row + r) * 2048 + col] = f2bf(clampf(acc[i][j][r] + bv));
      } else {  // V -> V^T
        const int d = col & 63;
        const int hh = (col - 2048) >> 6;
        #pragma unroll
        for (int r = 0; r < 4; ++r) {
          const int rr = row + r;
          const int bb = rr >> 11, ss = rr & 2047;
          vt[(size_t)(bb * 16 + hh) * 131072 + d * 2048 + ss] =
              f2bf(clampf(acc[i][j][r] + bv));
        }
      }
    }
  }
}

// ---------- GEMM2: out(f32) = ctx * w_proj^T + bias (FROZEN R14) ----------
__global__ __launch_bounds__(256) void gemm2_proj(
    const u16* __restrict__ A, const u16* __restrict__ Bt,
    const float* __restrict__ bias, float* __restrict__ out, int K) {
  __shared__ u16 As0[128 * 32], As1[128 * 32];
  __shared__ u16 Bs0[128 * 32], Bs1[128 * 32];
  const int tid = threadIdx.x;
  const int m0 = blockIdx.x * 128, n0 = blockIdx.y * 128;
  const int wave = tid >> 6, lane = tid & 63;
  const int quad = lane >> 4, l16 = lane & 15;
  const int wm = (wave >> 1) * 64, wn = (wave & 1) * 64;
  const int sr = (lane >> 2), sp = lane & 3;

  f32x4 acc[4][4] = {};
  const u16* gA = A + (size_t)(m0 + wave * 32 + sr) * K + sp * 8;
  const u16* gB = Bt + (size_t)(n0 + wave * 32 + sr) * K + sp * 8;

  for (int k0 = 0; k0 < K; k0 += 64) {
    #pragma unroll
    for (int t = 0; t < 2; ++t) {
      gll16(gA + (size_t)(t * 16) * K + k0,      &As0[(wave * 32 + t * 16) * 32]);
      gll16(gA + (size_t)(t * 16) * K + k0 + 32, &As1[(wave * 32 + t * 16) * 32]);
      gll16(gB + (size_t)(t * 16) * K + k0,      &Bs0[(wave * 32 + t * 16) * 32]);
      gll16(gB + (size_t)(t * 16) * K + k0 + 32, &Bs1[(wave * 32 + t * 16) * 32]);
    }
    __syncthreads();
    #pragma unroll
    for (int ks = 0; ks < 2; ++ks) {
      const u16* Ah = ks ? As1 : As0;
      const u16* Bh = ks ? Bs1 : Bs0;
      bf16x8 af[4], bfr[4];
      #pragma unroll
      for (int i = 0; i < 4; ++i)
        af[i] = *(const bf16x8*)&Ah[(wm + i * 16 + l16) * 32 + quad * 8];
      #pragma unroll
      for (int j = 0; j < 4; ++j)
        bfr[j] = *(const bf16x8*)&Bh[(wn + j * 16 + l16) * 32 + quad * 8];
      #pragma unroll
      for (int i = 0; i < 4; ++i)
        #pragma unroll
        for (int j = 0; j < 4; ++j)
          acc[i][j] = __builtin_amdgcn_mfma_f32_16x16x32_bf16(af[i], bfr[j], acc[i][j], 0, 0, 0);
    }
    __syncthreads();
  }

  #pragma unroll
  for (int i = 0; i < 4; ++i) {
    const int row = m0 + wm + i * 16 + quad * 4;
    #pragma unroll
    for (int j = 0; j < 4; ++j) {
      const int col = n0 + wn + j * 16 + l16;
      const float bv = bias[col];
      #pragma unroll
      for (int r = 0; r < 4; ++r)
        out[(size_t)(row + r) * 1024 + col] = clampf(acc[i][j][r] + bv);
    }
  }
}

// ---------- fused flash attention, v15 ----------
// Post-mortem v14 (86.7us): permlane+ones-MFMA landed as predicted (VALU
// 40.3us, MFMA 38.8us == new floor w/ lsum, conflicts 0). BONUS: compiler
// DCE'd `big` -> LDS 16384B and NOTHING broke (FETCH ~31MB) -- the "pin
// 4 blocks/CU via LDS pad" theory is refuted; drop the pad.
// v15 cuts the two remaining cheap VALU terms (pipes co-bound at ~45%):
//  1. c2 folded into Q at gemm1 -> exp2(s) direct (-32 v_mul/tile/wave).
//  2. hoisted zero f32x16 as C-in for the first QK MFMA of each kb
//     (-16-reg zero-init per kb if the compiler wasn't hoisting).
// Sync structure UNCHANGED from the proven v11/v13/v14 schedule.
__device__ __forceinline__ int swz(int row, int col) {
  const int key = (row ^ (row >> 2)) & 7;
  return row * 64 + (((col >> 3) ^ key) << 3) + (col & 7);
}

__global__ __launch_bounds__(256, 4) void attn_fused(
    const u16* __restrict__ qk, const u16* __restrict__ vt,
    u16* __restrict__ ctx) {
  __shared__ u16 Ks[64 * 64];
  __shared__ u16 VsT[64 * 64];
  const int bh = blockIdx.x, qt = blockIdx.y;
  const int b = bh >> 4, h = bh & 15;
  const int tid = threadIdx.x;
  const int w = tid >> 6, lane = tid & 63;
  const int l31 = lane & 31, hl = lane >> 5;
  const int qbase = qt * 128 + w * 32;

  // Q fragments (B-operand): lane l31 = q-col, elems d = ds*16 + hl*8 + e
  const u16* qptr = qk + (size_t)(b * 2048) * 2048 + h * 64;
  bf16x8 qf[4];
  #pragma unroll
  for (int ds = 0; ds < 4; ++ds)
    qf[ds] = *(const bf16x8*)(qptr + (size_t)(qbase + l31) * 2048 + ds * 16 + hl * 8);

  const u16* kptr = qk + (size_t)(b * 2048) * 2048 + 1024 + h * 64;
  const u16* vptr = vt + (size_t)bh * 131072;

  const int srow = tid >> 3, scol = (tid & 7) * 8;

  // loop-invariant LDS offsets
  const int st0 = swz(srow, scol);
  const int st1 = swz(srow + 32, scol);
  int off[2][4];
  #pragma unroll
  for (int a = 0; a < 2; ++a)
    #pragma unroll
    for (int d = 0; d < 4; ++d)
      off[a][d] = swz(a * 32 + l31, d * 16 + hl * 8);

  // loop-invariant global bases
  const u16* kB0 = kptr + (size_t)srow * 2048 + scol;
  const u16* kB1 = kptr + (size_t)(srow + 32) * 2048 + scol;
  const u16* vB0 = vptr + (size_t)srow * 2048 + scol;
  const u16* vB1 = vptr + (size_t)(srow + 32) * 2048 + scol;

  f32x16 o[2] = {};
  f32x16 lsum = {};
  const f32x16 fz = {};  // hoisted zero C-in for QK^T
  const short one = (short)0x3F80;  // bf16 1.0
  const bf16x8 ones = {one, one, one, one, one, one, one, one};

  bf16x8 k0 = *(const bf16x8*)kB0;
  bf16x8 k1 = *(const bf16x8*)kB1;
  bf16x8 v0 = *(const bf16x8*)vB0;
  bf16x8 v1 = *(const bf16x8*)vB1;

  for (int kv0 = 0; kv0 < 2048; kv0 += 64) {
    __syncthreads();
    *(bf16x8*)&Ks[st0]  = k0;
    *(bf16x8*)&Ks[st1]  = k1;
    *(bf16x8*)&VsT[st0] = v0;
    *(bf16x8*)&VsT[st1] = v1;
    __syncthreads();
    const int kvn = (kv0 + 64) & 2047;
    k0 = *(const bf16x8*)(kB0 + (size_t)kvn * 2048);
    k1 = *(const bf16x8*)(kB1 + (size_t)kvn * 2048);
    v0 = *(const bf16x8*)(vB0 + kvn);
    v1 = *(const bf16x8*)(vB1 + kvn);

    #pragma unroll
    for (int kb = 0; kb < 2; ++kb) {
      // QK^T swapped: s^T[k][q], lane col = q, regs = k rows
      f32x16 s;
      __builtin_amdgcn_s_setprio(1);
      {
        bf16x8 kf = *(const bf16x8*)&Ks[off[kb][0]];
        s = __builtin_amdgcn_mfma_f32_32x32x16_bf16(kf, qf[0], fz, 0, 0, 0);
      }
      #pragma unroll
      for (int ds = 1; ds < 4; ++ds) {
        bf16x8 kf = *(const bf16x8*)&Ks[off[kb][ds]];
        s = __builtin_amdgcn_mfma_f32_32x32x16_bf16(kf, qf[ds], s, 0, 0, 0);
      }
      __builtin_amdgcn_s_setprio(0);
      // exp2 in place (c2 pre-folded into Q by gemm1)
      #pragma unroll
      for (int r = 0; r < 16; ++r)
        s[r] = __builtin_amdgcn_exp2f(s[r]);
      // PV: A-frag via cvt_pk + permlane32_swap (no bpermute, no selects)
      #pragma unroll
      for (int ksl = 0; ksl < 2; ++ksl) {
        const int r0 = ksl * 8;
        unsigned cA = cvtpk(s[r0 + 0], s[r0 + 1]);
        unsigned cB = cvtpk(s[r0 + 2], s[r0 + 3]);
        unsigned cC = cvtpk(s[r0 + 4], s[r0 + 5]);
        unsigned cD = cvtpk(s[r0 + 6], s[r0 + 7]);
        // swap vdst.hi <-> vsrc.lo: cA becomes w0, cC becomes w2 (both halves)
        asm volatile("v_permlane32_swap_b32 %0, %1" : "+v"(cA), "+v"(cC));
        asm volatile("v_permlane32_swap_b32 %0, %1" : "+v"(cB), "+v"(cD));
        union { unsigned u[4]; bf16x8 v; } pf;
        pf.u[0] = cA;  // e=0,1
        pf.u[1] = cB;  // e=2,3
        pf.u[2] = cC;  // e=4,5
        pf.u[3] = cD;  // e=6,7
        const int kg = kb * 2 + ksl;
        __builtin_amdgcn_s_setprio(1);
        lsum = __builtin_amdgcn_mfma_f32_32x32x16_bf16(pf.v, ones, lsum, 0, 0, 0);
        #pragma unroll
        for (int db = 0; db < 2; ++db) {
          bf16x8 vf = *(const bf16x8*)&VsT[off[db][kg]];
          o[db] = __builtin_amdgcn_mfma_f32_32x32x16_bf16(pf.v, vf, o[db], 0, 0, 0);
        }
        __builtin_amdgcn_s_setprio(0);
      }
    }
  }

  u16* cbase = ctx + (size_t)(b * 2048) * 1024 + h * 64;
  #pragma unroll
  for (int r = 0; r < 16; ++r) {
    const int q0 = (r & 3) + 8 * (r >> 2) + 4 * hl;
    const float inv = 1.0f / lsum[r];
    const size_t qrow = (size_t)(qbase + q0);
    cbase[qrow * 1024 + l31]      = f2bf(o[0][r] * inv);
    cbase[qrow * 1024 + 32 + l31] = f2bf(o[1][r] * inv);
  }
}

extern "C" void kernel_launch(void* const* d_in, const int* in_sizes, int n_in,
                              void* d_out, int out_size, void* d_ws, size_t ws_size,
                              hipStream_t stream) {
  (void)out_size;
  const float *x = nullptr, *wq = nullptr, *bq = nullptr, *wp = nullptr, *bp = nullptr;
  for (int i = 0; i < n_in; ++i) {
    switch (in_sizes[i]) {
      case 8388608: x  = (const float*)d_in[i]; break;
      case 3145728: wq = (const float*)d_in[i]; break;
      case 3072:    bq = (const float*)d_in[i]; break;
      case 1048576: wp = (const float*)d_in[i]; break;
      case 1024:    bp = (const float*)d_in[i]; break;
      default: break;
    }
  }
  if (!x || !wq || !bq || !wp || !bp) {
    x  = (const float*)d_in[0]; wq = (const float*)d_in[1];
    bq = (const float*)d_in[2]; wp = (const float*)d_in[3];
    bp = (const float*)d_in[4];
  }
  float* out = (float*)d_out;

  const size_t NEED = 75497472;
  if (ws_size < NEED) return;

  char* ws = (char*)d_ws;
  u16* qkb = (u16*)(ws);              // [8192][2048] Q(pre-scaled),K
  u16* vt  = (u16*)(ws + 33554432);   // [64][64][2048] V^T
  u16* xbf = (u16*)(ws + 50331648);   // x_bf, then ctx
  u16* wT1 = (u16*)(ws + 67108864);
  u16* wT2 = (u16*)(ws + 73400320);

  convert_x<<<8192, 256, 0, stream>>>(x, xbf);
  transpose_f32_bf16<<<dim3(96, 32), 256, 0, stream>>>(wq, wT1, 1024, 3072);
  transpose_f32_bf16<<<dim3(32, 32), 256, 0, stream>>>(wp, wT2, 1024, 1024);
  gemm1_qkv<<<dim3(64, 24), 256, 0, stream>>>(xbf, wT1, bq, qkb, vt, 1024);
  attn_fused<<<dim3(64, 16), 256, 0, stream>>>(qkb, vt, xbf /*ctx*/);
  gemm2_proj<<<dim3(64, 8), 256, 0, stream>>>(xbf /*ctx*/, wT2, bp, out, 1024);
}

// Round 10
// 279.769 us; speedup vs baseline: 1.0082x; 1.0003x over previous
//
#include <hip/hip_runtime.h>

typedef unsigned short u16;
typedef __attribute__((ext_vector_type(8))) short bf16x8;   // 8 bf16 (4 VGPRs)
typedef __attribute__((ext_vector_type(4))) float f32x4;    // 16x16 MFMA C/D frag
typedef __attribute__((ext_vector_type(16))) float f32x16;  // 32x32 MFMA C/D frag

__device__ __forceinline__ float bf2f(u16 x) {
  union { unsigned u; float f; } v; v.u = ((unsigned)x) << 16; return v.f;
}
__device__ __forceinline__ u16 f2bf(float f) {
  union { float f; unsigned u; } v; v.f = f;
  unsigned r = v.u + 0x7FFFu + ((v.u >> 16) & 1u);  // RNE
  return (u16)(r >> 16);
}
__device__ __forceinline__ float clampf(float v) {
  return fmaxf(fminf(v, 1.0e4f), -1.0e4f);
}
// async global->LDS, 16B per lane; LDS dest = wave-uniform base + lane*16
__device__ __forceinline__ void gll16(const u16* g, u16* l) {
  __builtin_amdgcn_global_load_lds(
      (const __attribute__((address_space(1))) void*)g,
      (__attribute__((address_space(3))) void*)l, 16, 0, 0);
}
// pack two f32 -> one u32 of 2 bf16 (RNE), lo = first arg
__device__ __forceinline__ unsigned cvtpk(float lo, float hi) {
  unsigned r;
  asm("v_cvt_pk_bf16_f32 %0, %1, %2" : "=v"(r) : "v"(lo), "v"(hi));
  return r;
}

// ---------- convert x (f32) -> bf16 ----------
__global__ __launch_bounds__(256) void convert_x(
    const float* __restrict__ x, u16* __restrict__ xbf) {
  const int i0 = (blockIdx.x * 256 + threadIdx.x) * 4;
  const float4 v = *(const float4*)(x + i0);
  xbf[i0 + 0] = f2bf(v.x); xbf[i0 + 1] = f2bf(v.y);
  xbf[i0 + 2] = f2bf(v.z); xbf[i0 + 3] = f2bf(v.w);
}

// ---------- transpose f32 in[R][C] -> bf16 out[C][R] ----------
__global__ __launch_bounds__(256) void transpose_f32_bf16(
    const float* __restrict__ in, u16* __restrict__ out, int R, int C) {
  __shared__ u16 tile[32][33];
  const int bc = blockIdx.x * 32, br = blockIdx.y * 32;
  const int tx = threadIdx.x & 31, ty = threadIdx.x >> 5;
  #pragma unroll
  for (int i = ty; i < 32; i += 8)
    tile[i][tx] = f2bf(in[(size_t)(br + i) * C + bc + tx]);
  __syncthreads();
  #pragma unroll
  for (int i = ty; i < 32; i += 8)
    out[(size_t)(bc + i) * R + br + tx] = tile[tx][i];
}

// ---------- GEMM1: QKV projection (R15: Q output pre-scaled by c2) ----------
__global__ __launch_bounds__(256) void gemm1_qkv(
    const u16* __restrict__ A, const u16* __restrict__ Bt,
    const float* __restrict__ bias, u16* __restrict__ qk,
    u16* __restrict__ vt, int K) {
  __shared__ u16 As0[128 * 32], As1[128 * 32];
  __shared__ u16 Bs0[128 * 32], Bs1[128 * 32];
  const int tid = threadIdx.x;
  const int m0 = blockIdx.x * 128, n0 = blockIdx.y * 128;
  const int wave = tid >> 6, lane = tid & 63;
  const int quad = lane >> 4, l16 = lane & 15;
  const int wm = (wave >> 1) * 64, wn = (wave & 1) * 64;
  const int sr = (lane >> 2), sp = lane & 3;

  f32x4 acc[4][4] = {};
  const u16* gA = A + (size_t)(m0 + wave * 32 + sr) * K + sp * 8;
  const u16* gB = Bt + (size_t)(n0 + wave * 32 + sr) * K + sp * 8;

  for (int k0 = 0; k0 < K; k0 += 64) {
    #pragma unroll
    for (int t = 0; t < 2; ++t) {
      gll16(gA + (size_t)(t * 16) * K + k0,      &As0[(wave * 32 + t * 16) * 32]);
      gll16(gA + (size_t)(t * 16) * K + k0 + 32, &As1[(wave * 32 + t * 16) * 32]);
      gll16(gB + (size_t)(t * 16) * K + k0,      &Bs0[(wave * 32 + t * 16) * 32]);
      gll16(gB + (size_t)(t * 16) * K + k0 + 32, &Bs1[(wave * 32 + t * 16) * 32]);
    }
    __syncthreads();
    #pragma unroll
    for (int ks = 0; ks < 2; ++ks) {
      const u16* Ah = ks ? As1 : As0;
      const u16* Bh = ks ? Bs1 : Bs0;
      bf16x8 af[4], bfr[4];
      #pragma unroll
      for (int i = 0; i < 4; ++i)
        af[i] = *(const bf16x8*)&Ah[(wm + i * 16 + l16) * 32 + quad * 8];
      #pragma unroll
      for (int j = 0; j < 4; ++j)
        bfr[j] = *(const bf16x8*)&Bh[(wn + j * 16 + l16) * 32 + quad * 8];
      #pragma unroll
      for (int i = 0; i < 4; ++i)
        #pragma unroll
        for (int j = 0; j < 4; ++j)
          acc[i][j] = __builtin_amdgcn_mfma_f32_16x16x32_bf16(af[i], bfr[j], acc[i][j], 0, 0, 0);
    }
    __syncthreads();
  }

  const float c2q = 0.125f * 1.44269504088896340736f;
  #pragma unroll
  for (int i = 0; i < 4; ++i) {
    const int row = m0 + wm + i * 16 + quad * 4;
    #pragma unroll
    for (int j = 0; j < 4; ++j) {
      const int col = n0 + wn + j * 16 + l16;
      const float bv = bias[col];
      if (col < 1024) {  // Q: pre-scale by c2
        #pragma unroll
        for (int r = 0; r < 4; ++r)
          qk[(size_t)(row + r) * 2048 + col] = f2bf(clampf(acc[i][j][r] + bv) * c2q);
      } else if (col < 2048) {  // K: unscaled
        #pragma unroll
        for (int r = 0; r < 4; ++r)
          qk[(size_t)(row + r) * 2048 + col] = f2bf(clampf(acc[i][j][r] + bv));
      } else {  // V -> V^T
        const int d = col & 63;
        const int hh = (col - 2048) >> 6;
        #pragma unroll
        for (int r = 0; r < 4; ++r) {
          const int rr = row + r;
          const int bb = rr >> 11, ss = rr & 2047;
          vt[(size_t)(bb * 16 + hh) * 131072 + d * 2048 + ss] =
              f2bf(clampf(acc[i][j][r] + bv));
        }
      }
    }
  }
}

// ---------- GEMM2: out(f32) = ctx * w_proj^T + bias ----------
// R16: 64x128 tiles, grid (128,8) = 1024 blocks = 4 blocks/CU, 16 waves/CU.
// Old (64,8)=512 blocks was 2 blocks/CU = 2 waves/SIMD -- latency-starved
// (same structure collapses at small grids per m102 shape curve). Wave now
// computes 32x64 (acc[2][4]); staging: A 64 rows = 1 gll16-pair/wave,
// B 128 rows = 2 pairs/wave. LDS 24KB. Schedule/sync unchanged.
__global__ __launch_bounds__(256) void gemm2_proj(
    const u16* __restrict__ A, const u16* __restrict__ Bt,
    const float* __restrict__ bias, float* __restrict__ out, int K) {
  __shared__ u16 As0[64 * 32], As1[64 * 32];
  __shared__ u16 Bs0[128 * 32], Bs1[128 * 32];
  const int tid = threadIdx.x;
  const int m0 = blockIdx.x * 64, n0 = blockIdx.y * 128;
  const int wave = tid >> 6, lane = tid & 63;
  const int quad = lane >> 4, l16 = lane & 15;
  const int wm = (wave >> 1) * 32, wn = (wave & 1) * 64;
  const int sr = (lane >> 2), sp = lane & 3;

  f32x4 acc[2][4] = {};
  const u16* gA = A + (size_t)(m0 + wave * 16 + sr) * K + sp * 8;
  const u16* gB = Bt + (size_t)(n0 + wave * 32 + sr) * K + sp * 8;

  for (int k0 = 0; k0 < K; k0 += 64) {
    // A: 4 waves x 16 rows = 64 rows per 32-col half
    gll16(gA + k0,      &As0[(wave * 16) * 32]);
    gll16(gA + k0 + 32, &As1[(wave * 16) * 32]);
    // B: 4 waves x 2 x 16 rows = 128 rows per half
    #pragma unroll
    for (int t = 0; t < 2; ++t) {
      gll16(gB + (size_t)(t * 16) * K + k0,      &Bs0[(wave * 32 + t * 16) * 32]);
      gll16(gB + (size_t)(t * 16) * K + k0 + 32, &Bs1[(wave * 32 + t * 16) * 32]);
    }
    __syncthreads();
    #pragma unroll
    for (int ks = 0; ks < 2; ++ks) {
      const u16* Ah = ks ? As1 : As0;
      const u16* Bh = ks ? Bs1 : Bs0;
      bf16x8 af[2], bfr[4];
      #pragma unroll
      for (int i = 0; i < 2; ++i)
        af[i] = *(const bf16x8*)&Ah[(wm + i * 16 + l16) * 32 + quad * 8];
      #pragma unroll
      for (int j = 0; j < 4; ++j)
        bfr[j] = *(const bf16x8*)&Bh[(wn + j * 16 + l16) * 32 + quad * 8];
      #pragma unroll
      for (int i = 0; i < 2; ++i)
        #pragma unroll
        for (int j = 0; j < 4; ++j)
          acc[i][j] = __builtin_amdgcn_mfma_f32_16x16x32_bf16(af[i], bfr[j], acc[i][j], 0, 0, 0);
    }
    __syncthreads();
  }

  #pragma unroll
  for (int i = 0; i < 2; ++i) {
    const int row = m0 + wm + i * 16 + quad * 4;
    #pragma unroll
    for (int j = 0; j < 4; ++j) {
      const int col = n0 + wn + j * 16 + l16;
      const float bv = bias[col];
      #pragma unroll
      for (int r = 0; r < 4; ++r)
        out[(size_t)(row + r) * 1024 + col] = clampf(acc[i][j][r] + bv);
    }
  }
}

// ---------- fused flash attention, v15 (FROZEN R15: 81.7us) ----------
// MfmaUtil 48.3 (busy 39.5us ~= 37.2us floor), VALU 40.6, conflicts 0,
// combined pipes ~89% -- near work-inventory limit. Do not touch.
__device__ __forceinline__ int swz(int row, int col) {
  const int key = (row ^ (row >> 2)) & 7;
  return row * 64 + (((col >> 3) ^ key) << 3) + (col & 7);
}

__global__ __launch_bounds__(256, 4) void attn_fused(
    const u16* __restrict__ qk, const u16* __restrict__ vt,
    u16* __restrict__ ctx) {
  __shared__ u16 Ks[64 * 64];
  __shared__ u16 VsT[64 * 64];
  const int bh = blockIdx.x, qt = blockIdx.y;
  const int b = bh >> 4, h = bh & 15;
  const int tid = threadIdx.x;
  const int w = tid >> 6, lane = tid & 63;
  const int l31 = lane & 31, hl = lane >> 5;
  const int qbase = qt * 128 + w * 32;

  // Q fragments (B-operand): lane l31 = q-col, elems d = ds*16 + hl*8 + e
  const u16* qptr = qk + (size_t)(b * 2048) * 2048 + h * 64;
  bf16x8 qf[4];
  #pragma unroll
  for (int ds = 0; ds < 4; ++ds)
    qf[ds] = *(const bf16x8*)(qptr + (size_t)(qbase + l31) * 2048 + ds * 16 + hl * 8);

  const u16* kptr = qk + (size_t)(b * 2048) * 2048 + 1024 + h * 64;
  const u16* vptr = vt + (size_t)bh * 131072;

  const int srow = tid >> 3, scol = (tid & 7) * 8;

  // loop-invariant LDS offsets
  const int st0 = swz(srow, scol);
  const int st1 = swz(srow + 32, scol);
  int off[2][4];
  #pragma unroll
  for (int a = 0; a < 2; ++a)
    #pragma unroll
    for (int d = 0; d < 4; ++d)
      off[a][d] = swz(a * 32 + l31, d * 16 + hl * 8);

  // loop-invariant global bases
  const u16* kB0 = kptr + (size_t)srow * 2048 + scol;
  const u16* kB1 = kptr + (size_t)(srow + 32) * 2048 + scol;
  const u16* vB0 = vptr + (size_t)srow * 2048 + scol;
  const u16* vB1 = vptr + (size_t)(srow + 32) * 2048 + scol;

  f32x16 o[2] = {};
  f32x16 lsum = {};
  const f32x16 fz = {};  // hoisted zero C-in for QK^T
  const short one = (short)0x3F80;  // bf16 1.0
  const bf16x8 ones = {one, one, one, one, one, one, one, one};

  bf16x8 k0 = *(const bf16x8*)kB0;
  bf16x8 k1 = *(const bf16x8*)kB1;
  bf16x8 v0 = *(const bf16x8*)vB0;
  bf16x8 v1 = *(const bf16x8*)vB1;

  for (int kv0 = 0; kv0 < 2048; kv0 += 64) {
    __syncthreads();
    *(bf16x8*)&Ks[st0]  = k0;
    *(bf16x8*)&Ks[st1]  = k1;
    *(bf16x8*)&VsT[st0] = v0;
    *(bf16x8*)&VsT[st1] = v1;
    __syncthreads();
    const int kvn = (kv0 + 64) & 2047;
    k0 = *(const bf16x8*)(kB0 + (size_t)kvn * 2048);
    k1 = *(const bf16x8*)(kB1 + (size_t)kvn * 2048);
    v0 = *(const bf16x8*)(vB0 + kvn);
    v1 = *(const bf16x8*)(vB1 + kvn);

    #pragma unroll
    for (int kb = 0; kb < 2; ++kb) {
      // QK^T swapped: s^T[k][q], lane col = q, regs = k rows
      f32x16 s;
      __builtin_amdgcn_s_setprio(1);
      {
        bf16x8 kf = *(const bf16x8*)&Ks[off[kb][0]];
        s = __builtin_amdgcn_mfma_f32_32x32x16_bf16(kf, qf[0], fz, 0, 0, 0);
      }
      #pragma unroll
      for (int ds = 1; ds < 4; ++ds) {
        bf16x8 kf = *(const bf16x8*)&Ks[off[kb][ds]];
        s = __builtin_amdgcn_mfma_f32_32x32x16_bf16(kf, qf[ds], s, 0, 0, 0);
      }
      __builtin_amdgcn_s_setprio(0);
      // exp2 in place (c2 pre-folded into Q by gemm1)
      #pragma unroll
      for (int r = 0; r < 16; ++r)
        s[r] = __builtin_amdgcn_exp2f(s[r]);
      // PV: A-frag via cvt_pk + permlane32_swap (no bpermute, no selects)
      #pragma unroll
      for (int ksl = 0; ksl < 2; ++ksl) {
        const int r0 = ksl * 8;
        unsigned cA = cvtpk(s[r0 + 0], s[r0 + 1]);
        unsigned cB = cvtpk(s[r0 + 2], s[r0 + 3]);
        unsigned cC = cvtpk(s[r0 + 4], s[r0 + 5]);
        unsigned cD = cvtpk(s[r0 + 6], s[r0 + 7]);
        // swap vdst.hi <-> vsrc.lo: cA becomes w0, cC becomes w2 (both halves)
        asm volatile("v_permlane32_swap_b32 %0, %1" : "+v"(cA), "+v"(cC));
        asm volatile("v_permlane32_swap_b32 %0, %1" : "+v"(cB), "+v"(cD));
        union { unsigned u[4]; bf16x8 v; } pf;
        pf.u[0] = cA;  // e=0,1
        pf.u[1] = cB;  // e=2,3
        pf.u[2] = cC;  // e=4,5
        pf.u[3] = cD;  // e=6,7
        const int kg = kb * 2 + ksl;
        __builtin_amdgcn_s_setprio(1);
        lsum = __builtin_amdgcn_mfma_f32_32x32x16_bf16(pf.v, ones, lsum, 0, 0, 0);
        #pragma unroll
        for (int db = 0; db < 2; ++db) {
          bf16x8 vf = *(const bf16x8*)&VsT[off[db][kg]];
          o[db] = __builtin_amdgcn_mfma_f32_32x32x16_bf16(pf.v, vf, o[db], 0, 0, 0);
        }
        __builtin_amdgcn_s_setprio(0);
      }
    }
  }

  u16* cbase = ctx + (size_t)(b * 2048) * 1024 + h * 64;
  #pragma unroll
  for (int r = 0; r < 16; ++r) {
    const int q0 = (r & 3) + 8 * (r >> 2) + 4 * hl;
    const float inv = 1.0f / lsum[r];
    const size_t qrow = (size_t)(qbase + q0);
    cbase[qrow * 1024 + l31]      = f2bf(o[0][r] * inv);
    cbase[qrow * 1024 + 32 + l31] = f2bf(o[1][r] * inv);
  }
}

extern "C" void kernel_launch(void* const* d_in, const int* in_sizes, int n_in,
                              void* d_out, int out_size, void* d_ws, size_t ws_size,
                              hipStream_t stream) {
  (void)out_size;
  const float *x = nullptr, *wq = nullptr, *bq = nullptr, *wp = nullptr, *bp = nullptr;
  for (int i = 0; i < n_in; ++i) {
    switch (in_sizes[i]) {
      case 8388608: x  = (const float*)d_in[i]; break;
      case 3145728: wq = (const float*)d_in[i]; break;
      case 3072:    bq = (const float*)d_in[i]; break;
      case 1048576: wp = (const float*)d_in[i]; break;
      case 1024:    bp = (const float*)d_in[i]; break;
      default: break;
    }
  }
  if (!x || !wq || !bq || !wp || !bp) {
    x  = (const float*)d_in[0]; wq = (const float*)d_in[1];
    bq = (const float*)d_in[2]; wp = (const float*)d_in[3];
    bp = (const float*)d_in[4];
  }
  float* out = (float*)d_out;

  const size_t NEED = 75497472;
  if (ws_size < NEED) return;

  char* ws = (char*)d_ws;
  u16* qkb = (u16*)(ws);              // [8192][2048] Q(pre-scaled),K
  u16* vt  = (u16*)(ws + 33554432);   // [64][64][2048] V^T
  u16* xbf = (u16*)(ws + 50331648);   // x_bf, then ctx
  u16* wT1 = (u16*)(ws + 67108864);
  u16* wT2 = (u16*)(ws + 73400320);

  convert_x<<<8192, 256, 0, stream>>>(x, xbf);
  transpose_f32_bf16<<<dim3(96, 32), 256, 0, stream>>>(wq, wT1, 1024, 3072);
  transpose_f32_bf16<<<dim3(32, 32), 256, 0, stream>>>(wp, wT2, 1024, 1024);
  gemm1_qkv<<<dim3(64, 24), 256, 0, stream>>>(xbf, wT1, bq, qkb, vt, 1024);
  attn_fused<<<dim3(64, 16), 256, 0, stream>>>(qkb, vt, xbf /*ctx*/);
  gemm2_proj<<<dim3(128, 8), 256, 0, stream>>>(xbf /*ctx*/, wT2, bp, out, 1024);
}

// Round 11
// 276.082 us; speedup vs baseline: 1.0217x; 1.0134x over previous
//
#include <hip/hip_runtime.h>

typedef unsigned short u16;
typedef __attribute__((ext_vector_type(8))) short bf16x8;   // 8 bf16 (4 VGPRs)
typedef __attribute__((ext_vector_type(4))) float f32x4;    // 16x16 MFMA C/D frag
typedef __attribute__((ext_vector_type(16))) float f32x16;  // 32x32 MFMA C/D frag

__device__ __forceinline__ float bf2f(u16 x) {
  union { unsigned u; float f; } v; v.u = ((unsigned)x) << 16; return v.f;
}
__device__ __forceinline__ u16 f2bf(float f) {
  union { float f; unsigned u; } v; v.f = f;
  unsigned r = v.u + 0x7FFFu + ((v.u >> 16) & 1u);  // RNE
  return (u16)(r >> 16);
}
__device__ __forceinline__ float clampf(float v) {
  return fmaxf(fminf(v, 1.0e4f), -1.0e4f);
}
// async global->LDS, 16B per lane; LDS dest = wave-uniform base + lane*16
__device__ __forceinline__ void gll16(const u16* g, u16* l) {
  __builtin_amdgcn_global_load_lds(
      (const __attribute__((address_space(1))) void*)g,
      (__attribute__((address_space(3))) void*)l, 16, 0, 0);
}
// pack two f32 -> one u32 of 2 bf16 (RNE), lo = first arg
__device__ __forceinline__ unsigned cvtpk(float lo, float hi) {
  unsigned r;
  asm("v_cvt_pk_bf16_f32 %0, %1, %2" : "=v"(r) : "v"(lo), "v"(hi));
  return r;
}

// ---------- fused prep: convert x (f32->bf16) + both weight transposes ----
// R17: launch-count experiment. convert_x (8192 blocks) + transpose wq
// (3072 blocks) + transpose wp (1024 blocks) were 3 independent launches;
// fused into one 12288-block kernel (branch is block-uniform). 6 -> 4
// dispatches per iteration. Probes whether the ~30-70us gap between
// work-estimates and measured total is inter-kernel launch overhead.
__global__ __launch_bounds__(256) void fused_prep(
    const float* __restrict__ x,  u16* __restrict__ xbf,
    const float* __restrict__ wq, u16* __restrict__ wT1,
    const float* __restrict__ wp, u16* __restrict__ wT2) {
  __shared__ u16 tile[32][33];
  const int blk = blockIdx.x;
  if (blk < 8192) {
    // convert x -> bf16 (identical to proven convert_x)
    const int i0 = (blk * 256 + threadIdx.x) * 4;
    const float4 v = *(const float4*)(x + i0);
    xbf[i0 + 0] = f2bf(v.x); xbf[i0 + 1] = f2bf(v.y);
    xbf[i0 + 2] = f2bf(v.z); xbf[i0 + 3] = f2bf(v.w);
    return;
  }
  // weight transposes (identical tile logic to proven transpose_f32_bf16)
  const float* in; u16* outp; int R, C, bc, br;
  if (blk < 8192 + 3072) {
    const int u = blk - 8192;
    in = wq; outp = wT1; R = 1024; C = 3072;
    bc = (u % 96) * 32; br = (u / 96) * 32;
  } else {
    const int u = blk - 11264;
    in = wp; outp = wT2; R = 1024; C = 1024;
    bc = (u % 32) * 32; br = (u / 32) * 32;
  }
  const int tx = threadIdx.x & 31, ty = threadIdx.x >> 5;
  #pragma unroll
  for (int i = ty; i < 32; i += 8)
    tile[i][tx] = f2bf(in[(size_t)(br + i) * C + bc + tx]);
  __syncthreads();
  #pragma unroll
  for (int i = ty; i < 32; i += 8)
    outp[(size_t)(bc + i) * R + br + tx] = tile[tx][i];
}

// ---------- GEMM1: QKV projection (R15: Q output pre-scaled by c2) ----------
__global__ __launch_bounds__(256) void gemm1_qkv(
    const u16* __restrict__ A, const u16* __restrict__ Bt,
    const float* __restrict__ bias, u16* __restrict__ qk,
    u16* __restrict__ vt, int K) {
  __shared__ u16 As0[128 * 32], As1[128 * 32];
  __shared__ u16 Bs0[128 * 32], Bs1[128 * 32];
  const int tid = threadIdx.x;
  const int m0 = blockIdx.x * 128, n0 = blockIdx.y * 128;
  const int wave = tid >> 6, lane = tid & 63;
  const int quad = lane >> 4, l16 = lane & 15;
  const int wm = (wave >> 1) * 64, wn = (wave & 1) * 64;
  const int sr = (lane >> 2), sp = lane & 3;

  f32x4 acc[4][4] = {};
  const u16* gA = A + (size_t)(m0 + wave * 32 + sr) * K + sp * 8;
  const u16* gB = Bt + (size_t)(n0 + wave * 32 + sr) * K + sp * 8;

  for (int k0 = 0; k0 < K; k0 += 64) {
    #pragma unroll
    for (int t = 0; t < 2; ++t) {
      gll16(gA + (size_t)(t * 16) * K + k0,      &As0[(wave * 32 + t * 16) * 32]);
      gll16(gA + (size_t)(t * 16) * K + k0 + 32, &As1[(wave * 32 + t * 16) * 32]);
      gll16(gB + (size_t)(t * 16) * K + k0,      &Bs0[(wave * 32 + t * 16) * 32]);
      gll16(gB + (size_t)(t * 16) * K + k0 + 32, &Bs1[(wave * 32 + t * 16) * 32]);
    }
    __syncthreads();
    #pragma unroll
    for (int ks = 0; ks < 2; ++ks) {
      const u16* Ah = ks ? As1 : As0;
      const u16* Bh = ks ? Bs1 : Bs0;
      bf16x8 af[4], bfr[4];
      #pragma unroll
      for (int i = 0; i < 4; ++i)
        af[i] = *(const bf16x8*)&Ah[(wm + i * 16 + l16) * 32 + quad * 8];
      #pragma unroll
      for (int j = 0; j < 4; ++j)
        bfr[j] = *(const bf16x8*)&Bh[(wn + j * 16 + l16) * 32 + quad * 8];
      #pragma unroll
      for (int i = 0; i < 4; ++i)
        #pragma unroll
        for (int j = 0; j < 4; ++j)
          acc[i][j] = __builtin_amdgcn_mfma_f32_16x16x32_bf16(af[i], bfr[j], acc[i][j], 0, 0, 0);
    }
    __syncthreads();
  }

  const float c2q = 0.125f * 1.44269504088896340736f;
  #pragma unroll
  for (int i = 0; i < 4; ++i) {
    const int row = m0 + wm + i * 16 + quad * 4;
    #pragma unroll
    for (int j = 0; j < 4; ++j) {
      const int col = n0 + wn + j * 16 + l16;
      const float bv = bias[col];
      if (col < 1024) {  // Q: pre-scale by c2
        #pragma unroll
        for (int r = 0; r < 4; ++r)
          qk[(size_t)(row + r) * 2048 + col] = f2bf(clampf(acc[i][j][r] + bv) * c2q);
      } else if (col < 2048) {  // K: unscaled
        #pragma unroll
        for (int r = 0; r < 4; ++r)
          qk[(size_t)(row + r) * 2048 + col] = f2bf(clampf(acc[i][j][r] + bv));
      } else {  // V -> V^T
        const int d = col & 63;
        const int hh = (col - 2048) >> 6;
        #pragma unroll
        for (int r = 0; r < 4; ++r) {
          const int rr = row + r;
          const int bb = rr >> 11, ss = rr & 2047;
          vt[(size_t)(bb * 16 + hh) * 131072 + d * 2048 + ss] =
              f2bf(clampf(acc[i][j][r] + bv));
        }
      }
    }
  }
}

// ---------- GEMM2: out(f32) = ctx * w_proj^T + bias (R16 retile) ----------
__global__ __launch_bounds__(256) void gemm2_proj(
    const u16* __restrict__ A, const u16* __restrict__ Bt,
    const float* __restrict__ bias, float* __restrict__ out, int K) {
  __shared__ u16 As0[64 * 32], As1[64 * 32];
  __shared__ u16 Bs0[128 * 32], Bs1[128 * 32];
  const int tid = threadIdx.x;
  const int m0 = blockIdx.x * 64, n0 = blockIdx.y * 128;
  const int wave = tid >> 6, lane = tid & 63;
  const int quad = lane >> 4, l16 = lane & 15;
  const int wm = (wave >> 1) * 32, wn = (wave & 1) * 64;
  const int sr = (lane >> 2), sp = lane & 3;

  f32x4 acc[2][4] = {};
  const u16* gA = A + (size_t)(m0 + wave * 16 + sr) * K + sp * 8;
  const u16* gB = Bt + (size_t)(n0 + wave * 32 + sr) * K + sp * 8;

  for (int k0 = 0; k0 < K; k0 += 64) {
    gll16(gA + k0,      &As0[(wave * 16) * 32]);
    gll16(gA + k0 + 32, &As1[(wave * 16) * 32]);
    #pragma unroll
    for (int t = 0; t < 2; ++t) {
      gll16(gB + (size_t)(t * 16) * K + k0,      &Bs0[(wave * 32 + t * 16) * 32]);
      gll16(gB + (size_t)(t * 16) * K + k0 + 32, &Bs1[(wave * 32 + t * 16) * 32]);
    }
    __syncthreads();
    #pragma unroll
    for (int ks = 0; ks < 2; ++ks) {
      const u16* Ah = ks ? As1 : As0;
      const u16* Bh = ks ? Bs1 : Bs0;
      bf16x8 af[2], bfr[4];
      #pragma unroll
      for (int i = 0; i < 2; ++i)
        af[i] = *(const bf16x8*)&Ah[(wm + i * 16 + l16) * 32 + quad * 8];
      #pragma unroll
      for (int j = 0; j < 4; ++j)
        bfr[j] = *(const bf16x8*)&Bh[(wn + j * 16 + l16) * 32 + quad * 8];
      #pragma unroll
      for (int i = 0; i < 2; ++i)
        #pragma unroll
        for (int j = 0; j < 4; ++j)
          acc[i][j] = __builtin_amdgcn_mfma_f32_16x16x32_bf16(af[i], bfr[j], acc[i][j], 0, 0, 0);
    }
    __syncthreads();
  }

  #pragma unroll
  for (int i = 0; i < 2; ++i) {
    const int row = m0 + wm + i * 16 + quad * 4;
    #pragma unroll
    for (int j = 0; j < 4; ++j) {
      const int col = n0 + wn + j * 16 + l16;
      const float bv = bias[col];
      #pragma unroll
      for (int r = 0; r < 4; ++r)
        out[(size_t)(row + r) * 1024 + col] = clampf(acc[i][j][r] + bv);
    }
  }
}

// ---------- fused flash attention, v15 (FROZEN R15: 80.3us) ----------
// MfmaUtil 49.8, VALU 41.8, conflicts 0, combined ~91.6% -- at the
// work-inventory limit of this structure. Do not touch.
__device__ __forceinline__ int swz(int row, int col) {
  const int key = (row ^ (row >> 2)) & 7;
  return row * 64 + (((col >> 3) ^ key) << 3) + (col & 7);
}

__global__ __launch_bounds__(256, 4) void attn_fused(
    const u16* __restrict__ qk, const u16* __restrict__ vt,
    u16* __restrict__ ctx) {
  __shared__ u16 Ks[64 * 64];
  __shared__ u16 VsT[64 * 64];
  const int bh = blockIdx.x, qt = blockIdx.y;
  const int b = bh >> 4, h = bh & 15;
  const int tid = threadIdx.x;
  const int w = tid >> 6, lane = tid & 63;
  const int l31 = lane & 31, hl = lane >> 5;
  const int qbase = qt * 128 + w * 32;

  // Q fragments (B-operand): lane l31 = q-col, elems d = ds*16 + hl*8 + e
  const u16* qptr = qk + (size_t)(b * 2048) * 2048 + h * 64;
  bf16x8 qf[4];
  #pragma unroll
  for (int ds = 0; ds < 4; ++ds)
    qf[ds] = *(const bf16x8*)(qptr + (size_t)(qbase + l31) * 2048 + ds * 16 + hl * 8);

  const u16* kptr = qk + (size_t)(b * 2048) * 2048 + 1024 + h * 64;
  const u16* vptr = vt + (size_t)bh * 131072;

  const int srow = tid >> 3, scol = (tid & 7) * 8;

  // loop-invariant LDS offsets
  const int st0 = swz(srow, scol);
  const int st1 = swz(srow + 32, scol);
  int off[2][4];
  #pragma unroll
  for (int a = 0; a < 2; ++a)
    #pragma unroll
    for (int d = 0; d < 4; ++d)
      off[a][d] = swz(a * 32 + l31, d * 16 + hl * 8);

  // loop-invariant global bases
  const u16* kB0 = kptr + (size_t)srow * 2048 + scol;
  const u16* kB1 = kptr + (size_t)(srow + 32) * 2048 + scol;
  const u16* vB0 = vptr + (size_t)srow * 2048 + scol;
  const u16* vB1 = vptr + (size_t)(srow + 32) * 2048 + scol;

  f32x16 o[2] = {};
  f32x16 lsum = {};
  const f32x16 fz = {};  // hoisted zero C-in for QK^T
  const short one = (short)0x3F80;  // bf16 1.0
  const bf16x8 ones = {one, one, one, one, one, one, one, one};

  bf16x8 k0 = *(const bf16x8*)kB0;
  bf16x8 k1 = *(const bf16x8*)kB1;
  bf16x8 v0 = *(const bf16x8*)vB0;
  bf16x8 v1 = *(const bf16x8*)vB1;

  for (int kv0 = 0; kv0 < 2048; kv0 += 64) {
    __syncthreads();
    *(bf16x8*)&Ks[st0]  = k0;
    *(bf16x8*)&Ks[st1]  = k1;
    *(bf16x8*)&VsT[st0] = v0;
    *(bf16x8*)&VsT[st1] = v1;
    __syncthreads();
    const int kvn = (kv0 + 64) & 2047;
    k0 = *(const bf16x8*)(kB0 + (size_t)kvn * 2048);
    k1 = *(const bf16x8*)(kB1 + (size_t)kvn * 2048);
    v0 = *(const bf16x8*)(vB0 + kvn);
    v1 = *(const bf16x8*)(vB1 + kvn);

    #pragma unroll
    for (int kb = 0; kb < 2; ++kb) {
      // QK^T swapped: s^T[k][q], lane col = q, regs = k rows
      f32x16 s;
      __builtin_amdgcn_s_setprio(1);
      {
        bf16x8 kf = *(const bf16x8*)&Ks[off[kb][0]];
        s = __builtin_amdgcn_mfma_f32_32x32x16_bf16(kf, qf[0], fz, 0, 0, 0);
      }
      #pragma unroll
      for (int ds = 1; ds < 4; ++ds) {
        bf16x8 kf = *(const bf16x8*)&Ks[off[kb][ds]];
        s = __builtin_amdgcn_mfma_f32_32x32x16_bf16(kf, qf[ds], s, 0, 0, 0);
      }
      __builtin_amdgcn_s_setprio(0);
      // exp2 in place (c2 pre-folded into Q by gemm1)
      #pragma unroll
      for (int r = 0; r < 16; ++r)
        s[r] = __builtin_amdgcn_exp2f(s[r]);
      // PV: A-frag via cvt_pk + permlane32_swap (no bpermute, no selects)
      #pragma unroll
      for (int ksl = 0; ksl < 2; ++ksl) {
        const int r0 = ksl * 8;
        unsigned cA = cvtpk(s[r0 + 0], s[r0 + 1]);
        unsigned cB = cvtpk(s[r0 + 2], s[r0 + 3]);
        unsigned cC = cvtpk(s[r0 + 4], s[r0 + 5]);
        unsigned cD = cvtpk(s[r0 + 6], s[r0 + 7]);
        // swap vdst.hi <-> vsrc.lo: cA becomes w0, cC becomes w2 (both halves)
        asm volatile("v_permlane32_swap_b32 %0, %1" : "+v"(cA), "+v"(cC));
        asm volatile("v_permlane32_swap_b32 %0, %1" : "+v"(cB), "+v"(cD));
        union { unsigned u[4]; bf16x8 v; } pf;
        pf.u[0] = cA;  // e=0,1
        pf.u[1] = cB;  // e=2,3
        pf.u[2] = cC;  // e=4,5
        pf.u[3] = cD;  // e=6,7
        const int kg = kb * 2 + ksl;
        __builtin_amdgcn_s_setprio(1);
        lsum = __builtin_amdgcn_mfma_f32_32x32x16_bf16(pf.v, ones, lsum, 0, 0, 0);
        #pragma unroll
        for (int db = 0; db < 2; ++db) {
          bf16x8 vf = *(const bf16x8*)&VsT[off[db][kg]];
          o[db] = __builtin_amdgcn_mfma_f32_32x32x16_bf16(pf.v, vf, o[db], 0, 0, 0);
        }
        __builtin_amdgcn_s_setprio(0);
      }
    }
  }

  u16* cbase = ctx + (size_t)(b * 2048) * 1024 + h * 64;
  #pragma unroll
  for (int r = 0; r < 16; ++r) {
    const int q0 = (r & 3) + 8 * (r >> 2) + 4 * hl;
    const float inv = 1.0f / lsum[r];
    const size_t qrow = (size_t)(qbase + q0);
    cbase[qrow * 1024 + l31]      = f2bf(o[0][r] * inv);
    cbase[qrow * 1024 + 32 + l31] = f2bf(o[1][r] * inv);
  }
}

extern "C" void kernel_launch(void* const* d_in, const int* in_sizes, int n_in,
                              void* d_out, int out_size, void* d_ws, size_t ws_size,
                              hipStream_t stream) {
  (void)out_size;
  const float *x = nullptr, *wq = nullptr, *bq = nullptr, *wp = nullptr, *bp = nullptr;
  for (int i = 0; i < n_in; ++i) {
    switch (in_sizes[i]) {
      case 8388608: x  = (const float*)d_in[i]; break;
      case 3145728: wq = (const float*)d_in[i]; break;
      case 3072:    bq = (const float*)d_in[i]; break;
      case 1048576: wp = (const float*)d_in[i]; break;
      case 1024:    bp = (const float*)d_in[i]; break;
      default: break;
    }
  }
  if (!x || !wq || !bq || !wp || !bp) {
    x  = (const float*)d_in[0]; wq = (const float*)d_in[1];
    bq = (const float*)d_in[2]; wp = (const float*)d_in[3];
    bp = (const float*)d_in[4];
  }
  float* out = (float*)d_out;

  const size_t NEED = 75497472;
  if (ws_size < NEED) return;

  char* ws = (char*)d_ws;
  u16* qkb = (u16*)(ws);              // [8192][2048] Q(pre-scaled),K
  u16* vt  = (u16*)(ws + 33554432);   // [64][64][2048] V^T
  u16* xbf = (u16*)(ws + 50331648);   // x_bf, then ctx
  u16* wT1 = (u16*)(ws + 67108864);
  u16* wT2 = (u16*)(ws + 73400320);

  fused_prep<<<12288, 256, 0, stream>>>(x, xbf, wq, wT1, wp, wT2);
  gemm1_qkv<<<dim3(64, 24), 256, 0, stream>>>(xbf, wT1, bq, qkb, vt, 1024);
  attn_fused<<<dim3(64, 16), 256, 0, stream>>>(qkb, vt, xbf /*ctx*/);
  gemm2_proj<<<dim3(128, 8), 256, 0, stream>>>(xbf /*ctx*/, wT2, bp, out, 1024);
}